// Round 3
// baseline (103.498 us; speedup 1.0000x reference)
//
#include <hip/hip_runtime.h>
#include <hip/hip_bf16.h>

// ---------------------------------------------------------------------------
// Fused causal attention head: B=4, T=4096, E=128, D=64, fp32 in/out.
// prep_w (W -> WT bf16) -> proj (x@W MFMA, 1-wave blocks, bf16 q/k/v in ws)
// -> attn_partial (split-KV flash, double-buffered K/V LDS, reg prefetch)
// -> attn_combine (weighted merge of partials).
// ---------------------------------------------------------------------------

typedef __attribute__((ext_vector_type(4))) float  f32x4;
typedef __attribute__((ext_vector_type(8))) __bf16 bf16x8;
typedef __attribute__((ext_vector_type(8))) unsigned short u16x8;
typedef __attribute__((ext_vector_type(4))) unsigned short u16x4;

#define T_SEQ 4096
#define DH    64
#define EDIM  128
#define QB    64
#define KVB   64
#define NCH   8      // KV chunks per q-tile
#define CHUNK 512    // keys per chunk = 8 KVB tiles
#define KSTR  72
#define VSTR  76
#define PSTR  72

__device__ __forceinline__ unsigned short f2bf(float f) {
    unsigned int x = __builtin_bit_cast(unsigned int, f);
    unsigned int r = x + 0x7fffu + ((x >> 16) & 1u);
    return (unsigned short)(r >> 16);
}

__device__ __forceinline__ f32x4 mfma_bf16(u16x8 a, u16x8 b, f32x4 c) {
    return __builtin_amdgcn_mfma_f32_16x16x32_bf16(
        __builtin_bit_cast(bf16x8, a), __builtin_bit_cast(bf16x8, b), c, 0, 0, 0);
}

// --------------------------- prep_w -----------------------------------------
__global__ __launch_bounds__(256) void prep_w_kernel(
    const float* __restrict__ wq, const float* __restrict__ wk,
    const float* __restrict__ wv, unsigned short* __restrict__ wt)
{
    int o = blockIdx.x * 256 + threadIdx.x;
    int m   = o >> 13;
    int rem = o & 8191;
    int d = rem >> 7, e = rem & 127;
    const float* W = (m == 0) ? wq : (m == 1) ? wk : wv;
    wt[o] = f2bf(W[e * DH + d]);
}

// --------------------------- proj: 1 wave per 16 rows, no LDS ---------------
__global__ __launch_bounds__(64) void proj_kernel(
    const float* __restrict__ x, const unsigned short* __restrict__ wt,
    unsigned short* __restrict__ qw, unsigned short* __restrict__ kw,
    unsigned short* __restrict__ vw)
{
    const int l   = threadIdx.x;
    const int l15 = l & 15;
    const int lg  = l >> 4;
    const int row0 = blockIdx.x * 16;

    // A fragments straight from global fp32 x
    u16x8 af[4];
    #pragma unroll
    for (int kt = 0; kt < 4; ++kt) {
        const float* xp = x + (row0 + l15) * EDIM + kt * 32 + lg * 8;
        f32x4 a = *(const f32x4*)xp;
        f32x4 b = *(const f32x4*)(xp + 4);
        af[kt] = u16x8{ f2bf(a[0]), f2bf(a[1]), f2bf(a[2]), f2bf(a[3]),
                        f2bf(b[0]), f2bf(b[1]), f2bf(b[2]), f2bf(b[3]) };
    }

    unsigned short* outs[3] = { qw, kw, vw };
    #pragma unroll
    for (int m = 0; m < 3; ++m) {
        #pragma unroll
        for (int nt = 0; nt < 4; ++nt) {
            f32x4 acc = {};
            #pragma unroll
            for (int kt = 0; kt < 4; ++kt) {
                u16x8 bfrag = *(const u16x8*)(wt + (m * 64 + nt * 16 + l15) * EDIM
                                                 + kt * 32 + lg * 8);
                acc = mfma_bf16(af[kt], bfrag, acc);
            }
            const float sc = (m == 0) ? 0.125f : 1.0f;
            #pragma unroll
            for (int r = 0; r < 4; ++r)
                outs[m][(row0 + lg * 4 + r) * DH + nt * 16 + l15] = f2bf(acc[r] * sc);
        }
    }
}

// --------------------------- flash inner loop -------------------------------
struct FlashState {
    f32x4 o_acc[4];
    float m_run[4], l_run[4];
};

__device__ __forceinline__ void flash_range(
    const unsigned short* __restrict__ kg, const unsigned short* __restrict__ vg,
    unsigned short (*K_lds)[KVB * KSTR], unsigned short (*VT_lds)[DH * VSTR],
    unsigned short* P_lds,
    int base, int qbase, int kv_begin, int kv_end,
    const u16x8* qf, FlashState& st,
    int w, int l15, int lg, int tid)
{
    // prologue: stage first tile into buffer 0
    {
        const unsigned short* kp = kg + (base + kv_begin) * DH;
        const unsigned short* vp = vg + (base + kv_begin) * DH;
        #pragma unroll
        for (int i = 0; i < 4; ++i) {
            int f4 = tid + i * 256, row = f4 >> 4, c = (f4 & 15) * 4;
            u16x4 kk = *(const u16x4*)(kp + row * DH + c);
            *(u16x4*)&K_lds[0][row * KSTR + c] = kk;
            u16x4 vv = *(const u16x4*)(vp + row * DH + c);
            #pragma unroll
            for (int j = 0; j < 4; ++j) VT_lds[0][(c + j) * VSTR + row] = vv[j];
        }
    }
    __syncthreads();

    int cur = 0;
    unsigned short* pw = &P_lds[w * 16 * PSTR];

    for (int kv0 = kv_begin; kv0 < kv_end; kv0 += KVB) {
        const bool pre = (kv0 + KVB < kv_end);

        // issue next tile's global loads early (latency hides under compute)
        u16x4 kr[4], vr[4];
        if (pre) {
            const unsigned short* kp = kg + (base + kv0 + KVB) * DH;
            const unsigned short* vp = vg + (base + kv0 + KVB) * DH;
            #pragma unroll
            for (int i = 0; i < 4; ++i) {
                int f4 = tid + i * 256, row = f4 >> 4, c = (f4 & 15) * 4;
                kr[i] = *(const u16x4*)(kp + row * DH + c);
                vr[i] = *(const u16x4*)(vp + row * DH + c);
            }
        }

        // ---- S = Q K^T ----
        f32x4 s[4];
        __builtin_amdgcn_s_setprio(1);
        #pragma unroll
        for (int nt = 0; nt < 4; ++nt) {
            f32x4 acc = {};
            #pragma unroll
            for (int kt = 0; kt < 2; ++kt) {
                u16x8 kf = *(const u16x8*)&K_lds[cur][(nt * 16 + l15) * KSTR + kt * 32 + lg * 8];
                acc = mfma_bf16(qf[kt], kf, acc);
            }
            s[nt] = acc;
        }
        __builtin_amdgcn_s_setprio(0);

        // ---- causal mask (diagonal tile only) ----
        if (kv0 == qbase) {
            #pragma unroll
            for (int nt = 0; nt < 4; ++nt)
                #pragma unroll
                for (int r = 0; r < 4; ++r) {
                    int qi = w * 16 + lg * 4 + r;
                    int kj = nt * 16 + l15;
                    if (kj > qi) s[nt][r] = -1e30f;
                }
        }

        // ---- online softmax (rescale-skip) ----
        float sc4[4];
        bool grow = false;
        #pragma unroll
        for (int r = 0; r < 4; ++r) {
            float m0 = fmaxf(fmaxf(s[0][r], s[1][r]), fmaxf(s[2][r], s[3][r]));
            m0 = fmaxf(m0, __shfl_xor(m0, 1));
            m0 = fmaxf(m0, __shfl_xor(m0, 2));
            m0 = fmaxf(m0, __shfl_xor(m0, 4));
            m0 = fmaxf(m0, __shfl_xor(m0, 8));

            float mold = st.m_run[r];
            float mnew = fmaxf(mold, m0);
            sc4[r] = __expf(mold - mnew);           // ==1.0 when no growth
            grow  |= (m0 > mold);
            st.m_run[r] = mnew;
            st.l_run[r] *= sc4[r];

            float rs = 0.0f;
            #pragma unroll
            for (int nt = 0; nt < 4; ++nt) {
                float p0 = __expf(s[nt][r] - mnew);
                s[nt][r] = p0;
                rs += p0;
            }
            rs += __shfl_xor(rs, 1);
            rs += __shfl_xor(rs, 2);
            rs += __shfl_xor(rs, 4);
            rs += __shfl_xor(rs, 8);
            st.l_run[r] += rs;
        }
        if (__any(grow)) {
            #pragma unroll
            for (int dt = 0; dt < 4; ++dt)
                #pragma unroll
                for (int r = 0; r < 4; ++r) st.o_acc[dt][r] *= sc4[r];
        }

        // ---- P -> LDS (wave-private), C-layout -> A-layout ----
        #pragma unroll
        for (int nt = 0; nt < 4; ++nt)
            #pragma unroll
            for (int r = 0; r < 4; ++r)
                pw[(lg * 4 + r) * PSTR + nt * 16 + l15] = f2bf(s[nt][r]);

        // ---- O += P V ----
        __builtin_amdgcn_s_setprio(1);
        #pragma unroll
        for (int kt = 0; kt < 2; ++kt) {
            u16x8 pf = *(const u16x8*)&pw[l15 * PSTR + kt * 32 + lg * 8];
            #pragma unroll
            for (int dt = 0; dt < 4; ++dt) {
                const unsigned short* vp2 = &VT_lds[cur][(dt * 16 + l15) * VSTR + kt * 32 + lg * 8];
                u16x4 va = *(const u16x4*)vp2;
                u16x4 vb = *(const u16x4*)(vp2 + 4);
                u16x8 vf = __builtin_shufflevector(va, vb, 0, 1, 2, 3, 4, 5, 6, 7);
                st.o_acc[dt] = mfma_bf16(pf, vf, st.o_acc[dt]);
            }
        }
        __builtin_amdgcn_s_setprio(0);

        // ---- write prefetched tile into the other buffer ----
        if (pre) {
            #pragma unroll
            for (int i = 0; i < 4; ++i) {
                int f4 = tid + i * 256, row = f4 >> 4, c = (f4 & 15) * 4;
                *(u16x4*)&K_lds[cur ^ 1][row * KSTR + c] = kr[i];
                #pragma unroll
                for (int j = 0; j < 4; ++j)
                    VT_lds[cur ^ 1][(c + j) * VSTR + row] = vr[i][j];
            }
        }
        __syncthreads();
        cur ^= 1;
    }
}

// --------------------------- phase 1: split-KV partials ---------------------
__global__ __launch_bounds__(256) void attn_partial_kernel(
    const unsigned short* __restrict__ qg, const unsigned short* __restrict__ kg,
    const unsigned short* __restrict__ vg,
    float* __restrict__ po, float* __restrict__ pm, float* __restrict__ pl)
{
    const int bid = blockIdx.x;          // (b*64 + qt)*8 + ch
    const int ch  = bid & (NCH - 1);
    const int qt  = (bid >> 3) & 63;
    const int b   = bid >> 9;
    if (ch * 8 > qt) return;             // beyond causal range

    __shared__ unsigned short K_lds[2][KVB * KSTR];
    __shared__ unsigned short VT_lds[2][DH * VSTR];
    __shared__ unsigned short P_lds[4 * 16 * PSTR];

    const int tid = threadIdx.x;
    const int w   = tid >> 6;
    const int l   = tid & 63;
    const int l15 = l & 15;
    const int lg  = l >> 4;

    const int qbase = qt * QB;
    const int base  = b * T_SEQ;
    const int kv_begin = ch * CHUNK;
    const int kv_end   = min(kv_begin + CHUNK, qbase + QB);

    u16x8 qf[2];
    {
        const unsigned short* qrow = qg + (base + qbase + w * 16 + l15) * DH;
        qf[0] = *(const u16x8*)(qrow +  0 + lg * 8);
        qf[1] = *(const u16x8*)(qrow + 32 + lg * 8);
    }

    FlashState st;
    #pragma unroll
    for (int dt = 0; dt < 4; ++dt) st.o_acc[dt] = f32x4{};
    #pragma unroll
    for (int r = 0; r < 4; ++r) { st.m_run[r] = -1e30f; st.l_run[r] = 0.0f; }

    flash_range(kg, vg, K_lds, VT_lds, P_lds, base, qbase, kv_begin, kv_end,
                qf, st, w, l15, lg, tid);

    const int pidx = (b * 64 + qt) * NCH + ch;
    float* pob = po + pidx * (QB * DH);
    #pragma unroll
    for (int r = 0; r < 4; ++r) {
        int row = w * 16 + lg * 4 + r;
        #pragma unroll
        for (int dt = 0; dt < 4; ++dt)
            pob[row * DH + dt * 16 + l15] = st.o_acc[dt][r];
        if (l15 == 0) {
            pm[pidx * QB + row] = st.m_run[r];
            pl[pidx * QB + row] = st.l_run[r];
        }
    }
}

// --------------------------- phase 2: combine -------------------------------
__global__ __launch_bounds__(256) void attn_combine_kernel(
    const float* __restrict__ po, const float* __restrict__ pm,
    const float* __restrict__ pl, float* __restrict__ out)
{
    const int tb  = blockIdx.x;          // b*64 + qt
    const int qt  = tb & 63;
    const int nch = (qt >> 3) + 1;
    const int row = threadIdx.x >> 2;
    const int dq  = (threadIdx.x & 3) * 16;
    const int base_p = tb * NCH;

    float mstar = -1e30f;
    float m_i[NCH];
    #pragma unroll
    for (int i = 0; i < NCH; ++i) {
        if (i < nch) {
            m_i[i] = pm[(base_p + i) * QB + row];
            mstar = fmaxf(mstar, m_i[i]);
        }
    }
    float w_i[NCH];
    float lsum = 0.0f;
    #pragma unroll
    for (int i = 0; i < NCH; ++i) {
        if (i < nch) {
            w_i[i] = __expf(m_i[i] - mstar);
            lsum += w_i[i] * pl[(base_p + i) * QB + row];
        }
    }
    const float inv = 1.0f / lsum;

    f32x4 acc[4] = {};
    #pragma unroll
    for (int i = 0; i < NCH; ++i) {
        if (i < nch) {
            const float* p = po + (base_p + i) * (QB * DH) + row * DH + dq;
            #pragma unroll
            for (int j = 0; j < 4; ++j) {
                f32x4 v = *(const f32x4*)(p + j * 4);
                acc[j] += w_i[i] * v;
            }
        }
    }
    float* o = out + (tb * QB + row) * DH + dq;
    #pragma unroll
    for (int j = 0; j < 4; ++j)
        *(f32x4*)(o + j * 4) = acc[j] * inv;
}

// --------------------------- fallback: single-kernel flash ------------------
__global__ __launch_bounds__(256) void attn_kernel(
    const unsigned short* __restrict__ qg, const unsigned short* __restrict__ kg,
    const unsigned short* __restrict__ vg, float* __restrict__ out)
{
    __shared__ unsigned short K_lds[2][KVB * KSTR];
    __shared__ unsigned short VT_lds[2][DH * VSTR];
    __shared__ unsigned short P_lds[4 * 16 * PSTR];

    const int tid = threadIdx.x;
    const int w   = tid >> 6;
    const int l   = tid & 63;
    const int l15 = l & 15;
    const int lg  = l >> 4;

    const int bid   = blockIdx.x;
    const int b     = bid >> 6;
    const int qt    = bid & 63;
    const int qbase = qt * QB;
    const int base  = b * T_SEQ;

    u16x8 qf[2];
    {
        const unsigned short* qrow = qg + (base + qbase + w * 16 + l15) * DH;
        qf[0] = *(const u16x8*)(qrow +  0 + lg * 8);
        qf[1] = *(const u16x8*)(qrow + 32 + lg * 8);
    }

    FlashState st;
    #pragma unroll
    for (int dt = 0; dt < 4; ++dt) st.o_acc[dt] = f32x4{};
    #pragma unroll
    for (int r = 0; r < 4; ++r) { st.m_run[r] = -1e30f; st.l_run[r] = 0.0f; }

    flash_range(kg, vg, K_lds, VT_lds, P_lds, base, qbase, 0, qbase + QB,
                qf, st, w, l15, lg, tid);

    const int orow0 = base + qbase + w * 16;
    #pragma unroll
    for (int r = 0; r < 4; ++r) {
        float inv = 1.0f / st.l_run[r];
        #pragma unroll
        for (int dt = 0; dt < 4; ++dt) {
            int row = orow0 + lg * 4 + r;
            out[row * DH + dt * 16 + l15] = st.o_acc[dt][r] * inv;
        }
    }
}

// ---------------------------------------------------------------------------
extern "C" void kernel_launch(void* const* d_in, const int* in_sizes, int n_in,
                              void* d_out, int out_size, void* d_ws, size_t ws_size,
                              hipStream_t stream)
{
    const float* x  = (const float*)d_in[0];
    const float* wq = (const float*)d_in[1];
    const float* wk = (const float*)d_in[2];
    const float* wv = (const float*)d_in[3];
    float* out = (float*)d_out;

    unsigned short* wt = (unsigned short*)d_ws;
    unsigned short* qw = (unsigned short*)((char*)d_ws + 65536);
    unsigned short* kw = qw + 16384 * DH;
    unsigned short* vw = kw + 16384 * DH;

    const size_t po_off = 65536u + 3u * 16384u * DH * 2u;
    const size_t po_sz  = (size_t)2048 * QB * DH * 4;
    const size_t pm_off = po_off + po_sz;
    const size_t pl_off = pm_off + (size_t)2048 * QB * 4;
    const size_t need   = pl_off + (size_t)2048 * QB * 4;

    prep_w_kernel<<<96, 256, 0, stream>>>(wq, wk, wv, wt);
    proj_kernel<<<1024, 64, 0, stream>>>(x, wt, qw, kw, vw);

    if (ws_size >= need) {
        float* po = (float*)((char*)d_ws + po_off);
        float* pm = (float*)((char*)d_ws + pm_off);
        float* pl = (float*)((char*)d_ws + pl_off);
        attn_partial_kernel<<<4 * 64 * NCH, 256, 0, stream>>>(qw, kw, vw, po, pm, pl);
        attn_combine_kernel<<<256, 256, 0, stream>>>(po, pm, pl, out);
    } else {
        attn_kernel<<<256, 256, 0, stream>>>(qw, kw, vw, out);
    }
}

// Round 4
// 101.175 us; speedup vs baseline: 1.0230x; 1.0230x over previous
//
#include <hip/hip_runtime.h>
#include <hip/hip_bf16.h>

// ---------------------------------------------------------------------------
// Fused causal attention head: B=4, T=4096, E=128, D=64, fp32 in/out.
// prep_w (W -> WT bf16) -> proj (x@W MFMA; q,k row-major bf16; V TRANSPOSED
// to vt[d][t] bf16) -> attn_partial (wave-independent split-KV flash:
// 1 wave = 32 q-rows x 512-key chunk, K/V B-fragments loaded directly from
// global (L2-resident), no barriers, only wave-private P LDS)
// -> attn_combine (weighted merge of partials).
// ---------------------------------------------------------------------------

typedef __attribute__((ext_vector_type(4))) float  f32x4;
typedef __attribute__((ext_vector_type(8))) __bf16 bf16x8;
typedef __attribute__((ext_vector_type(8))) unsigned short u16x8;
typedef __attribute__((ext_vector_type(4))) unsigned short u16x4;

#define T_SEQ 4096
#define DH    64
#define EDIM  128
#define KVB   64
#define NCH   8      // KV chunks per 64-row q-tile group (partial storage)
#define CHUNK 512
#define PSTR  72     // P_lds row stride (u16)

__device__ __forceinline__ unsigned short f2bf(float f) {
    unsigned int x = __builtin_bit_cast(unsigned int, f);
    unsigned int r = x + 0x7fffu + ((x >> 16) & 1u);
    return (unsigned short)(r >> 16);
}

__device__ __forceinline__ f32x4 mfma_bf16(u16x8 a, u16x8 b, f32x4 c) {
    return __builtin_amdgcn_mfma_f32_16x16x32_bf16(
        __builtin_bit_cast(bf16x8, a), __builtin_bit_cast(bf16x8, b), c, 0, 0, 0);
}

// --------------------------- prep_w -----------------------------------------
__global__ __launch_bounds__(256) void prep_w_kernel(
    const float* __restrict__ wq, const float* __restrict__ wk,
    const float* __restrict__ wv, unsigned short* __restrict__ wt)
{
    int o = blockIdx.x * 256 + threadIdx.x;
    int m   = o >> 13;
    int rem = o & 8191;
    int d = rem >> 7, e = rem & 127;
    const float* W = (m == 0) ? wq : (m == 1) ? wk : wv;
    wt[o] = f2bf(W[e * DH + d]);
}

// --------------------------- proj: q,k row-major; v transposed --------------
__global__ __launch_bounds__(64) void proj_kernel(
    const float* __restrict__ x, const unsigned short* __restrict__ wt,
    unsigned short* __restrict__ qw, unsigned short* __restrict__ kw,
    unsigned short* __restrict__ vt)
{
    const int l   = threadIdx.x;
    const int l15 = l & 15;
    const int lg  = l >> 4;
    const int row0 = blockIdx.x * 16;      // global row (b*4096 + t)
    const int b    = row0 >> 12;
    const int t0   = row0 & 4095;

    // A fragments straight from global fp32 x
    u16x8 af[4];
    #pragma unroll
    for (int kt = 0; kt < 4; ++kt) {
        const float* xp = x + (row0 + l15) * EDIM + kt * 32 + lg * 8;
        f32x4 a = *(const f32x4*)xp;
        f32x4 bb = *(const f32x4*)(xp + 4);
        af[kt] = u16x8{ f2bf(a[0]), f2bf(a[1]), f2bf(a[2]), f2bf(a[3]),
                        f2bf(bb[0]), f2bf(bb[1]), f2bf(bb[2]), f2bf(bb[3]) };
    }

    unsigned short* outs[2] = { qw, kw };
    #pragma unroll
    for (int m = 0; m < 2; ++m) {
        #pragma unroll
        for (int nt = 0; nt < 4; ++nt) {
            f32x4 acc = {};
            #pragma unroll
            for (int kt = 0; kt < 4; ++kt) {
                u16x8 bfrag = *(const u16x8*)(wt + (m * 64 + nt * 16 + l15) * EDIM
                                                 + kt * 32 + lg * 8);
                acc = mfma_bf16(af[kt], bfrag, acc);
            }
            const float sc = (m == 0) ? 0.125f : 1.0f;  // fold 1/sqrt(64) into q
            #pragma unroll
            for (int r = 0; r < 4; ++r)
                outs[m][(row0 + lg * 4 + r) * DH + nt * 16 + l15] = f2bf(acc[r] * sc);
        }
    }

    // v: store transposed vt[b][d][t]
    #pragma unroll
    for (int nt = 0; nt < 4; ++nt) {
        f32x4 acc = {};
        #pragma unroll
        for (int kt = 0; kt < 4; ++kt) {
            u16x8 bfrag = *(const u16x8*)(wt + (2 * 64 + nt * 16 + l15) * EDIM
                                             + kt * 32 + lg * 8);
            acc = mfma_bf16(af[kt], bfrag, acc);
        }
        u16x4 pv = { f2bf(acc[0]), f2bf(acc[1]), f2bf(acc[2]), f2bf(acc[3]) };
        *(u16x4*)(vt + ((size_t)(b * DH + nt * 16 + l15)) * T_SEQ + t0 + lg * 4) = pv;
    }
}

// --------------------------- flash core: 1 wave, 32 q-rows ------------------
struct St32 {
    f32x4 o[2][4];
    float m[2][4], l[2][4];
};

__device__ __forceinline__ void flash32(
    const unsigned short* __restrict__ kp,   // K for this batch, [t][d]
    const unsigned short* __restrict__ vp,   // V^T for this batch, [d][t]
    unsigned short (*P_lds)[16 * PSTR],
    int qrow0, int kv_begin, int kv_end,
    const u16x8 qf[2][2], St32& st, int l15, int lg)
{
    for (int kv0 = kv_begin; kv0 < kv_end; kv0 += KVB) {
        // ---- K B-fragments straight from global (L2-resident) ----
        u16x8 kf[4][2];
        #pragma unroll
        for (int nt = 0; nt < 4; ++nt)
            #pragma unroll
            for (int kt = 0; kt < 2; ++kt)
                kf[nt][kt] = *(const u16x8*)(kp + (kv0 + nt * 16 + l15) * DH
                                                + kt * 32 + lg * 8);

        // ---- S = Q K^T : 2 row-tiles x 4 col-tiles ----
        f32x4 s[2][4];
        __builtin_amdgcn_s_setprio(1);
        #pragma unroll
        for (int rt = 0; rt < 2; ++rt)
            #pragma unroll
            for (int nt = 0; nt < 4; ++nt) {
                f32x4 a = {};
                a = mfma_bf16(qf[rt][0], kf[nt][0], a);
                a = mfma_bf16(qf[rt][1], kf[nt][1], a);
                s[rt][nt] = a;
            }
        __builtin_amdgcn_s_setprio(0);

        // ---- causal mask (tiles straddling the diagonal) ----
        if (kv0 + KVB - 1 > qrow0) {
            #pragma unroll
            for (int rt = 0; rt < 2; ++rt)
                #pragma unroll
                for (int nt = 0; nt < 4; ++nt)
                    #pragma unroll
                    for (int r = 0; r < 4; ++r) {
                        int qi = qrow0 + rt * 16 + lg * 4 + r;
                        int kj = kv0 + nt * 16 + l15;
                        if (kj > qi) s[rt][nt][r] = -1e30f;
                    }
        }

        // ---- online softmax (rescale-skip) ----
        float sc4[2][4];
        bool grow = false;
        #pragma unroll
        for (int rt = 0; rt < 2; ++rt)
            #pragma unroll
            for (int r = 0; r < 4; ++r) {
                float m0 = fmaxf(fmaxf(s[rt][0][r], s[rt][1][r]),
                                 fmaxf(s[rt][2][r], s[rt][3][r]));
                m0 = fmaxf(m0, __shfl_xor(m0, 1));
                m0 = fmaxf(m0, __shfl_xor(m0, 2));
                m0 = fmaxf(m0, __shfl_xor(m0, 4));
                m0 = fmaxf(m0, __shfl_xor(m0, 8));

                float mold = st.m[rt][r];
                float mnew = fmaxf(mold, m0);
                sc4[rt][r] = __expf(mold - mnew);
                grow |= (m0 > mold);
                st.m[rt][r] = mnew;
                st.l[rt][r] *= sc4[rt][r];

                float rs = 0.0f;
                #pragma unroll
                for (int nt = 0; nt < 4; ++nt) {
                    float p0 = __expf(s[rt][nt][r] - mnew);
                    s[rt][nt][r] = p0;
                    rs += p0;
                }
                rs += __shfl_xor(rs, 1);
                rs += __shfl_xor(rs, 2);
                rs += __shfl_xor(rs, 4);
                rs += __shfl_xor(rs, 8);
                st.l[rt][r] += rs;
            }
        if (__any(grow)) {
            #pragma unroll
            for (int rt = 0; rt < 2; ++rt)
                #pragma unroll
                for (int dt = 0; dt < 4; ++dt)
                    #pragma unroll
                    for (int r = 0; r < 4; ++r)
                        st.o[rt][dt][r] *= sc4[rt][r];
        }

        // ---- P -> wave-private LDS (C-layout -> A-layout) ----
        #pragma unroll
        for (int rt = 0; rt < 2; ++rt)
            #pragma unroll
            for (int nt = 0; nt < 4; ++nt)
                #pragma unroll
                for (int r = 0; r < 4; ++r)
                    P_lds[rt][(lg * 4 + r) * PSTR + nt * 16 + l15] = f2bf(s[rt][nt][r]);

        // ---- O += P V  (V^T B-fragments straight from global vt) ----
        __builtin_amdgcn_s_setprio(1);
        #pragma unroll
        for (int kt = 0; kt < 2; ++kt) {
            u16x8 pf0 = *(const u16x8*)&P_lds[0][l15 * PSTR + kt * 32 + lg * 8];
            u16x8 pf1 = *(const u16x8*)&P_lds[1][l15 * PSTR + kt * 32 + lg * 8];
            #pragma unroll
            for (int dt = 0; dt < 4; ++dt) {
                u16x8 vf = *(const u16x8*)(vp + (size_t)(dt * 16 + l15) * T_SEQ
                                              + kv0 + kt * 32 + lg * 8);
                st.o[0][dt] = mfma_bf16(pf0, vf, st.o[0][dt]);
                st.o[1][dt] = mfma_bf16(pf1, vf, st.o[1][dt]);
            }
        }
        __builtin_amdgcn_s_setprio(0);
    }
}

// --------------------------- phase 1: split-KV partials ---------------------
__global__ __launch_bounds__(64, 3) void attn_partial_kernel(
    const unsigned short* __restrict__ qg, const unsigned short* __restrict__ kg,
    const unsigned short* __restrict__ vt,
    float* __restrict__ po, float* __restrict__ pm, float* __restrict__ pl)
{
    const int bid = blockIdx.x;          // (b*128 + q32)*8 + ch
    const int ch  = bid & (NCH - 1);
    const int q32 = (bid >> 3) & 127;
    const int b   = bid >> 10;
    if (ch * 16 > q32) return;           // beyond causal range

    __shared__ unsigned short P_lds[2][16 * PSTR];

    const int l   = threadIdx.x;
    const int l15 = l & 15;
    const int lg  = l >> 4;

    const int qrow0 = q32 * 32;
    const int base  = b * T_SEQ;
    const int kvb   = ch * CHUNK;
    const int kve   = min(kvb + CHUNK, qrow0 + 32);

    u16x8 qf[2][2];
    #pragma unroll
    for (int rt = 0; rt < 2; ++rt) {
        const unsigned short* qrow = qg + (base + qrow0 + rt * 16 + l15) * DH;
        qf[rt][0] = *(const u16x8*)(qrow +  0 + lg * 8);
        qf[rt][1] = *(const u16x8*)(qrow + 32 + lg * 8);
    }

    St32 st;
    #pragma unroll
    for (int rt = 0; rt < 2; ++rt)
        #pragma unroll
        for (int dt = 0; dt < 4; ++dt) st.o[rt][dt] = f32x4{};
    #pragma unroll
    for (int rt = 0; rt < 2; ++rt)
        #pragma unroll
        for (int r = 0; r < 4; ++r) { st.m[rt][r] = -1e30f; st.l[rt][r] = 0.0f; }

    flash32(kg + (size_t)base * DH, vt + (size_t)b * DH * T_SEQ,
            P_lds, qrow0, kvb, kve, qf, st, l15, lg);

    // partials keyed by 64-row tile group
    const int qt   = q32 >> 1;
    const int pidx = (b * 64 + qt) * NCH + ch;
    const int rr0  = (q32 & 1) * 32;
    float* pob = po + (size_t)pidx * 4096;
    #pragma unroll
    for (int rt = 0; rt < 2; ++rt)
        #pragma unroll
        for (int r = 0; r < 4; ++r) {
            int row = rr0 + rt * 16 + lg * 4 + r;
            #pragma unroll
            for (int dt = 0; dt < 4; ++dt)
                pob[row * DH + dt * 16 + l15] = st.o[rt][dt][r];
            if (l15 == 0) {
                pm[pidx * 64 + row] = st.m[rt][r];
                pl[pidx * 64 + row] = st.l[rt][r];
            }
        }
}

// --------------------------- phase 2: combine -------------------------------
__global__ __launch_bounds__(256) void attn_combine_kernel(
    const float* __restrict__ po, const float* __restrict__ pm,
    const float* __restrict__ pl, float* __restrict__ out)
{
    const int tb  = blockIdx.x;          // b*64 + qt
    const int qt  = tb & 63;
    const int row = threadIdx.x >> 2;
    const int dq  = (threadIdx.x & 3) * 16;
    const int q32 = qt * 2 + (row >> 5);
    const int nch = (q32 >> 4) + 1;
    const int base_p = tb * NCH;

    float mstar = -1e30f;
    float m_i[NCH];
    #pragma unroll
    for (int i = 0; i < NCH; ++i) {
        if (i < nch) {
            m_i[i] = pm[(base_p + i) * 64 + row];
            mstar = fmaxf(mstar, m_i[i]);
        }
    }
    float w_i[NCH];
    float lsum = 0.0f;
    #pragma unroll
    for (int i = 0; i < NCH; ++i) {
        if (i < nch) {
            w_i[i] = __expf(m_i[i] - mstar);
            lsum += w_i[i] * pl[(base_p + i) * 64 + row];
        }
    }
    const float inv = 1.0f / lsum;

    f32x4 acc[4] = {};
    #pragma unroll
    for (int i = 0; i < NCH; ++i) {
        if (i < nch) {
            const float* p = po + (size_t)(base_p + i) * 4096 + row * DH + dq;
            #pragma unroll
            for (int j = 0; j < 4; ++j) {
                f32x4 v = *(const f32x4*)(p + j * 4);
                acc[j] += w_i[i] * v;
            }
        }
    }
    float* o = out + (size_t)(tb * 64 + row) * DH + dq;
    #pragma unroll
    for (int j = 0; j < 4; ++j)
        *(f32x4*)(o + j * 4) = acc[j] * inv;
}

// --------------------------- fallback: direct (no partials) -----------------
__global__ __launch_bounds__(64, 3) void attn_direct_kernel(
    const unsigned short* __restrict__ qg, const unsigned short* __restrict__ kg,
    const unsigned short* __restrict__ vt, float* __restrict__ out)
{
    const int bid = blockIdx.x;          // b*128 + q32
    const int q32 = bid & 127;
    const int b   = bid >> 7;

    __shared__ unsigned short P_lds[2][16 * PSTR];

    const int l   = threadIdx.x;
    const int l15 = l & 15;
    const int lg  = l >> 4;

    const int qrow0 = q32 * 32;
    const int base  = b * T_SEQ;

    u16x8 qf[2][2];
    #pragma unroll
    for (int rt = 0; rt < 2; ++rt) {
        const unsigned short* qrow = qg + (base + qrow0 + rt * 16 + l15) * DH;
        qf[rt][0] = *(const u16x8*)(qrow +  0 + lg * 8);
        qf[rt][1] = *(const u16x8*)(qrow + 32 + lg * 8);
    }

    St32 st;
    #pragma unroll
    for (int rt = 0; rt < 2; ++rt)
        #pragma unroll
        for (int dt = 0; dt < 4; ++dt) st.o[rt][dt] = f32x4{};
    #pragma unroll
    for (int rt = 0; rt < 2; ++rt)
        #pragma unroll
        for (int r = 0; r < 4; ++r) { st.m[rt][r] = -1e30f; st.l[rt][r] = 0.0f; }

    flash32(kg + (size_t)base * DH, vt + (size_t)b * DH * T_SEQ,
            P_lds, qrow0, 0, qrow0 + 32, qf, st, l15, lg);

    #pragma unroll
    for (int rt = 0; rt < 2; ++rt)
        #pragma unroll
        for (int r = 0; r < 4; ++r) {
            int row = base + qrow0 + rt * 16 + lg * 4 + r;
            float inv = 1.0f / st.l[rt][r];
            #pragma unroll
            for (int dt = 0; dt < 4; ++dt)
                out[(size_t)row * DH + dt * 16 + l15] = st.o[rt][dt][r] * inv;
        }
}

// ---------------------------------------------------------------------------
extern "C" void kernel_launch(void* const* d_in, const int* in_sizes, int n_in,
                              void* d_out, int out_size, void* d_ws, size_t ws_size,
                              hipStream_t stream)
{
    const float* x  = (const float*)d_in[0];
    const float* wq = (const float*)d_in[1];
    const float* wk = (const float*)d_in[2];
    const float* wv = (const float*)d_in[3];
    float* out = (float*)d_out;

    // ws layout:
    //   wt  bf16 [3][64][128]   @ 0        (reserve 64 KB)
    //   qw  bf16 [16384][64]    @ 65536    (2 MB)
    //   kw  bf16 [16384][64]    @ +2 MB
    //   vt  bf16 [4][64][4096]  @ +4 MB    (V transposed per batch)
    //   po  f32 [2048][64][64]  @ +6 MB    (32 MB)
    //   pm/pl f32 [2048][64]    (512 KB each)
    unsigned short* wt = (unsigned short*)d_ws;
    unsigned short* qw = (unsigned short*)((char*)d_ws + 65536);
    unsigned short* kw = qw + (size_t)16384 * DH;
    unsigned short* vt = kw + (size_t)16384 * DH;

    const size_t po_off = 65536u + 3u * 16384u * DH * 2u;
    const size_t po_sz  = (size_t)2048 * 64 * 64 * 4;
    const size_t pm_off = po_off + po_sz;
    const size_t pl_off = pm_off + (size_t)2048 * 64 * 4;
    const size_t need   = pl_off + (size_t)2048 * 64 * 4;

    prep_w_kernel<<<96, 256, 0, stream>>>(wq, wk, wv, wt);
    proj_kernel<<<1024, 64, 0, stream>>>(x, wt, qw, kw, vt);

    if (ws_size >= need) {
        float* po = (float*)((char*)d_ws + po_off);
        float* pm = (float*)((char*)d_ws + pm_off);
        float* pl = (float*)((char*)d_ws + pl_off);
        attn_partial_kernel<<<4 * 128 * NCH, 64, 0, stream>>>(qw, kw, vt, po, pm, pl);
        attn_combine_kernel<<<256, 256, 0, stream>>>(po, pm, pl, out);
    } else {
        attn_direct_kernel<<<4 * 128, 64, 0, stream>>>(qw, kw, vt, out);
    }
}